// Round 5
// baseline (936.264 us; speedup 1.0000x reference)
//
#include <hip/hip_runtime.h>
#include <math.h>
#include <stdint.h>

#define N_NODES 100000
#define N_FEAT  512
#define HIDDEN  256
#define N_CLS   40
#define N_EDGES 1600000
#define K_HOPS  10

#define NPART   8                    // src partitions for L2-locality edge ordering
#define PSZ     12500                // nodes per src-part
#define NPN     (NPART * N_NODES)    // 800000 virtual CSR rows (dst, src_part)
#define SCANB   782                  // ceil((NPN+1)/1024)

#define PB      51                   // nodes per prop block (255 active threads * 5)
#define PGRID   ((N_NODES + PB - 1) / PB)   // 1961
#define ECAP    2048                 // LDS epair slots (block avg ~870)

typedef __attribute__((ext_vector_type(8))) short short8;   // 8 bf16
typedef __attribute__((ext_vector_type(4))) float f4_t;

__device__ __forceinline__ short f2bf(float f) {
    union { float f; unsigned u; } x; x.f = f;
    unsigned r = x.u + 0x7fffu + ((x.u >> 16) & 1u);  // RNE
    return (short)(r >> 16);
}

__device__ __forceinline__ float bf2f(short b) {
    union { unsigned u; float f; } x;
    x.u = ((unsigned)(unsigned short)b) << 16;
    return x.f;
}

// packed f32x2 -> bf16x2 (RNE), single HW instr; no builtin on gfx950
__device__ __forceinline__ unsigned cvtpk(float lo, float hi) {
    unsigned r;
    asm("v_cvt_pk_bf16_f32 %0, %1, %2" : "=v"(r) : "v"(lo), "v"(hi));
    return r;
}

// ---------------------------------------------------------------- prep kernels

__global__ __launch_bounds__(256) void init_degp_kernel(int* __restrict__ degp) {
    int idx = blockIdx.x * 256 + threadIdx.x;
    if (idx < NPN) {
        int v = idx >> 3, p = idx & 7;
        degp[idx] = (p == v / PSZ) ? 1 : 0;
    }
}

__global__ __launch_bounds__(256) void count_dst_kernel(const int* __restrict__ src,
                                                        const int* __restrict__ dst,
                                                        int* __restrict__ degp) {
    int e = blockIdx.x * 256 + threadIdx.x;
    if (e < N_EDGES) atomicAdd(&degp[dst[e] * NPART + src[e] / PSZ], 1);
}

__global__ __launch_bounds__(256) void rsqrt_deg_kernel(const int* __restrict__ degp,
                                                        float* __restrict__ d) {
    int v = blockIdx.x * 256 + threadIdx.x;
    if (v < N_NODES) {
        int s = 0;
#pragma unroll
        for (int p = 0; p < NPART; ++p) s += degp[v * NPART + p];
        d[v] = rsqrtf((float)s);
    }
}

// ---- 3-phase device-wide exclusive scan of degp -> rowptrp/cursor

__global__ __launch_bounds__(1024) void scan_partial_kernel(const int* __restrict__ degp,
                                                            int* __restrict__ blocksum) {
    __shared__ int s[1024];
    int t = threadIdx.x;
    int idx = blockIdx.x * 1024 + t;
    s[t] = (idx < NPN) ? degp[idx] : 0;
    __syncthreads();
#pragma unroll
    for (int off = 512; off > 0; off >>= 1) {
        if (t < off) s[t] += s[t + off];
        __syncthreads();
    }
    if (t == 0) blocksum[blockIdx.x] = s[0];
}

__global__ __launch_bounds__(1024) void scan_blocks_kernel(const int* __restrict__ blocksum,
                                                           int* __restrict__ blockoff) {
    __shared__ int s[1024];
    int t = threadIdx.x;
    int v = (t < SCANB) ? blocksum[t] : 0;
    s[t] = v;
    __syncthreads();
#pragma unroll
    for (int off = 1; off < 1024; off <<= 1) {
        int add = (t >= off) ? s[t - off] : 0;
        __syncthreads();
        s[t] += add;
        __syncthreads();
    }
    if (t < SCANB) blockoff[t] = s[t] - v;  // exclusive
}

__global__ __launch_bounds__(1024) void scan_write_kernel(const int* __restrict__ degp,
                                                          const int* __restrict__ blockoff,
                                                          int* __restrict__ rowptrp,
                                                          int* __restrict__ cursor) {
    __shared__ int s[1024];
    int t = threadIdx.x;
    int idx = blockIdx.x * 1024 + t;
    int v = (idx < NPN) ? degp[idx] : 0;
    s[t] = v;
    __syncthreads();
#pragma unroll
    for (int off = 1; off < 1024; off <<= 1) {
        int add = (t >= off) ? s[t - off] : 0;
        __syncthreads();
        s[t] += add;
        __syncthreads();
    }
    int pre = s[t] - v + blockoff[blockIdx.x];  // exclusive prefix
    if (idx <= NPN) rowptrp[idx] = pre;
    if (idx < NPN) cursor[idx] = pre;
}

// epair.x holds PRE-SCALED h_lo byte offset (u*64); h_hi offset = x>>2
__global__ __launch_bounds__(256) void scatter_edges_kernel(const int* __restrict__ src,
                                                            const int* __restrict__ dst,
                                                            const float* __restrict__ d,
                                                            int* __restrict__ cursor,
                                                            int2* __restrict__ epair) {
    int e = blockIdx.x * 256 + threadIdx.x;
    if (e >= N_EDGES) return;
    int u = src[e], v = dst[e];
    int pos = atomicAdd(&cursor[v * NPART + u / PSZ], 1);
    int2 p;
    p.x = u * 64;
    p.y = __float_as_int(d[u] * d[v]);
    epair[pos] = p;
}

__global__ __launch_bounds__(256) void scatter_self_kernel(const float* __restrict__ d,
                                                           int* __restrict__ cursor,
                                                           int2* __restrict__ epair) {
    int v = blockIdx.x * 256 + threadIdx.x;
    if (v >= N_NODES) return;
    int pos = atomicAdd(&cursor[v * NPART + v / PSZ], 1);
    float dv = d[v];
    int2 p;
    p.x = v * 64;
    p.y = __float_as_int(dv * dv);
    epair[pos] = p;
}

// W1 [512][256] f32 -> W1T [256][512] bf16 (col-major: per-col k contiguous)
__global__ __launch_bounds__(256) void cvt_w1_kernel(const float* __restrict__ W1,
                                                     short* __restrict__ W1T) {
    int lin = blockIdx.x * 256 + threadIdx.x;  // 131072
    int k = lin >> 8, n = lin & 255;
    W1T[n * 512 + k] = f2bf(W1[lin]);
}

// W2 [256][40] f32 -> W2T [64][256] bf16, rows >=40 zero
__global__ __launch_bounds__(256) void cvt_w2_kernel(const float* __restrict__ W2,
                                                     short* __restrict__ W2T) {
    int lin = blockIdx.x * 256 + threadIdx.x;  // 16384
    int n = lin >> 8, k = lin & 255;
    W2T[lin] = (n < N_CLS) ? f2bf(W2[k * N_CLS + n]) : (short)0;
}

// ---------------------------------------------------------------- fused MLP (MFMA)
// Block = 256 thr (4 waves), 64 rows. bf16 A-tile [64][72] (144B stride = clean
// 2-way banks, proven 1.8e6-conflict pattern), double-buffered, ONE raw
// s_barrier + lgkmcnt(0) per kt (no vmcnt drain!). feat tile and W1T fragments
// register-prefetched one kt ahead; all vmcnt waits are compiler-counted and
// never drain the in-flight prefetches.
__global__ __launch_bounds__(256) void mlp_kernel(const float* __restrict__ feat,
                                                  const short* __restrict__ W1T,
                                                  const float* __restrict__ b1,
                                                  const short* __restrict__ W2T,
                                                  const float* __restrict__ b2,
                                                  const float* __restrict__ temp,
                                                  short* __restrict__ h_lo,
                                                  short* __restrict__ h_hi,
                                                  float* __restrict__ TH) {
    __shared__ union {
        short A[2][64][72];                                // 18432 B (K-loop)
        short sH[64][264];                                 // 33792 B (phase B in)
        struct { short Ho[64][40]; float To[64][40]; } o;  // 15360 B (epilogue)
    } S;

    const int tid = threadIdx.x;
    const int rbase = blockIdx.x * 64;
    const int lane = tid & 63;
    const int wv = tid >> 6;       // wave 0..3
    const int quad = lane >> 4;    // 0..3
    const int l15 = lane & 15;

    f4_t acc[4][4];
#pragma unroll
    for (int m = 0; m < 4; ++m)
#pragma unroll
        for (int n = 0; n < 4; ++n) acc[m][n] = (f4_t)0.f;

    // staging: thread owns row tid>>2, float-quarter tid&3 (16 floats / kt)
    const int srow = tid >> 2;
    const int scol = (tid & 3) * 16;
    int growc = rbase + srow;
    if (growc >= N_NODES) growc = N_NODES - 1;   // clamp; masked in epilogue
    const float* fp = feat + (size_t)growc * N_FEAT + scol;

    f4_t fR0, fR1, fR2, fR3;   // feat prefetch (one kt ahead)
    short8 bR[8];              // W1T fragment prefetch (one kt ahead)

#define LOADF(KT)                                                   \
    { const f4_t* p_ = (const f4_t*)(fp + (KT) * 64);               \
      fR0 = p_[0]; fR1 = p_[1]; fR2 = p_[2]; fR3 = p_[3]; }

#define LOADB(KT)                                                   \
    { const short* wb_ = W1T + (KT) * 64;                           \
      _Pragma("unroll")                                             \
      for (int kk2 = 0; kk2 < 2; ++kk2)                             \
          _Pragma("unroll")                                         \
          for (int n = 0; n < 4; ++n)                               \
              bR[kk2 * 4 + n] = *(const short8*)(                   \
                  wb_ + (wv * 64 + n * 16 + l15) * 512 + kk2 * 32 + quad * 8); }

#define CVTWR(BUF)                                                  \
    { union { unsigned u[4]; short8 s; } xlo_, xhi_;                \
      xlo_.u[0] = cvtpk(fR0[0], fR0[1]); xlo_.u[1] = cvtpk(fR0[2], fR0[3]); \
      xlo_.u[2] = cvtpk(fR1[0], fR1[1]); xlo_.u[3] = cvtpk(fR1[2], fR1[3]); \
      xhi_.u[0] = cvtpk(fR2[0], fR2[1]); xhi_.u[1] = cvtpk(fR2[2], fR2[3]); \
      xhi_.u[2] = cvtpk(fR3[0], fR3[1]); xhi_.u[3] = cvtpk(fR3[2], fR3[3]); \
      short8* dp_ = (short8*)&S.A[BUF][srow][scol];                 \
      dp_[0] = xlo_.s; dp_[1] = xhi_.s; }

#define BARRIER()                                                   \
    asm volatile("s_waitcnt lgkmcnt(0)" ::: "memory");              \
    __builtin_amdgcn_s_barrier();                                   \
    __builtin_amdgcn_sched_barrier(0);

    // prologue: tile0 -> A[0]; bR <- kt0 frags; tile1 in regs
    LOADF(0);
    LOADB(0);
    CVTWR(0);      // waits fR (tile0); bR loads stay in flight
    LOADF(1);
    BARRIER();

#pragma unroll
    for (int kt = 0; kt < 8; ++kt) {
        const int cb = kt & 1;
        // MFMA on tile kt (A[cb] in LDS, bR in regs)
#pragma unroll
        for (int kk2 = 0; kk2 < 2; ++kk2) {
            short8 af[4];
#pragma unroll
            for (int m = 0; m < 4; ++m)
                af[m] = *(const short8*)&S.A[cb][m * 16 + l15][kk2 * 32 + quad * 8];
#pragma unroll
            for (int m = 0; m < 4; ++m)
#pragma unroll
                for (int n = 0; n < 4; ++n)
                    acc[m][n] = __builtin_amdgcn_mfma_f32_16x16x32_bf16(
                        af[m], bR[kk2 * 4 + n], acc[m][n], 0, 0, 0);
        }
        if (kt < 7) {
            LOADB(kt + 1);   // refill bR right after last use; lands under next kt
            CVTWR(cb ^ 1);   // tile kt+1 (regs loaded last iter) -> other LDS buf
        }
        if (kt < 6) LOADF(kt + 2);
        BARRIER();
    }
#undef LOADF
#undef LOADB
#undef CVTWR

    // bias + relu -> sH (A dead; all waves past final barrier)
#pragma unroll
    for (int n = 0; n < 4; ++n) {
        int col = wv * 64 + n * 16 + l15;
        float bb = b1[col];
#pragma unroll
        for (int m = 0; m < 4; ++m)
#pragma unroll
            for (int r = 0; r < 4; ++r) {
                float v = acc[m][n][r] + bb;
                S.sH[m * 16 + quad * 4 + r][col] = f2bf(v > 0.f ? v : 0.f);
            }
    }
    __syncthreads();

    // phase B: out = sH @ W2 + b2 ; W2 fragments from L1/L2 (32 KB, hot)
    f4_t accB[3];
#pragma unroll
    for (int n = 0; n < 3; ++n) accB[n] = (f4_t)0.f;
#pragma unroll
    for (int kk = 0; kk < 256; kk += 32) {
        short8 a = *(const short8*)&S.sH[wv * 16 + l15][kk + quad * 8];
#pragma unroll
        for (int n = 0; n < 3; ++n) {
            short8 b = *(const short8*)(W2T + (n * 16 + l15) * 256 + kk + quad * 8);
            accB[n] = __builtin_amdgcn_mfma_f32_16x16x32_bf16(a, b, accB[n], 0, 0, 0);
        }
    }
    __syncthreads();  // sH reads done -> epilogue staging may overwrite

    float t0 = temp[0];
#pragma unroll
    for (int n = 0; n < 3; ++n) {
        int col = n * 16 + l15;
        if (col < N_CLS) {
            float bb = b2[col];
#pragma unroll
            for (int r = 0; r < 4; ++r) {
                int row = wv * 16 + quad * 4 + r;
                float v = accB[n][r] + bb;
                S.o.Ho[row][col] = f2bf(v);
                S.o.To[row][col] = t0 * v;
            }
        }
    }
    __syncthreads();

    // coalesced writes: h_lo (32 bf16/row), h_hi (8 bf16/row), TH (40 f32/row)
    int rows = N_NODES - rbase; if (rows > 64) rows = 64;
    int nlo = rows * 4;   // short8 chunks of h_lo
    for (int i = tid; i < nlo; i += 256) {
        int row = i >> 2, part = i & 3;
        *(short8*)(h_lo + (size_t)(rbase + row) * 32 + part * 8) =
            *(const short8*)&S.o.Ho[row][part * 8];
    }
    for (int i = tid; i < rows; i += 256)
        *(short8*)(h_hi + (size_t)(rbase + i) * 8) = *(const short8*)&S.o.Ho[i][32];
    int nt = rows * 10;   // f4 chunks of TH
    for (int i = tid; i < nt; i += 256)
        *(f4_t*)(TH + (size_t)rbase * N_CLS + i * 4) =
            *(const f4_t*)((const float*)&S.o.To[0][0] + i * 4);
}

// ---------------------------------------------------------------- propagation
// Block = 51 nodes x 5 lanes. epair slice staged in LDS. h split: lanes c=0..3
// gather ONE 64B line from h_lo[N][32]; lane c=4 gathers 16B from the 1.6MB
// h_hi[N][8] (L2-super-hot). Per-edge line traffic 128B -> ~66B.
__global__ __launch_bounds__(256, 8) void prop_kernel(const short* __restrict__ h_lo,
                                                      const short* __restrict__ h_hi,
                                                      short* __restrict__ hn_lo,
                                                      short* __restrict__ hn_hi,
                                                      const int* __restrict__ rowptrp,
                                                      const int2* __restrict__ epair,
                                                      float* __restrict__ TH,
                                                      const float* __restrict__ temp,
                                                      int kidx) {
    __shared__ long long sE[ECAP];
    __shared__ int sRP[64];

    const int t = threadIdx.x;
    const int v0 = blockIdx.x * PB;
    int nmax = N_NODES - v0; if (nmax > PB) nmax = PB;
    if (t <= nmax) sRP[t] = rowptrp[(v0 + t) * NPART];
    __syncthreads();
    const int S0 = sRP[0];
    const int count = sRP[nmax] - S0;

    const int n = t / 5;
    const int c = t - n * 5;
    const bool act = (n < nmax) && (t < 255);
    const int js = act ? (sRP[n] - S0) : 0;
    const int je = act ? (sRP[n + 1] - S0) : 0;
    const unsigned sh = (c < 4) ? 0u : 2u;            // x = u*64; h_hi off = x>>2
    const char* hB = (c < 4) ? ((const char*)h_lo + c * 16) : (const char*)h_hi;

    f4_t a0 = (f4_t)0.f, a1 = (f4_t)0.f;
    int j = js;
    for (int base = 0; base < count; base += ECAP) {
        int lim = count - base; if (lim > ECAP) lim = ECAP;
        __syncthreads();
        for (int i = t; i < lim; i += 256)
            sE[i] = *(const long long*)(epair + (size_t)(S0 + base + i));
        __syncthreads();
        int jend = je - base; if (jend > lim) jend = lim;
        int jj = j - base;
        for (; jj + 4 <= jend; jj += 4) {
            long long r0 = sE[jj], r1 = sE[jj + 1], r2 = sE[jj + 2], r3 = sE[jj + 3];
            short8 h0 = *(const short8*)(hB + (((unsigned)(int)r0) >> sh));
            short8 h1 = *(const short8*)(hB + (((unsigned)(int)r1) >> sh));
            short8 h2 = *(const short8*)(hB + (((unsigned)(int)r2) >> sh));
            short8 h3 = *(const short8*)(hB + (((unsigned)(int)r3) >> sh));
            float w0 = __int_as_float((int)(r0 >> 32));
            float w1 = __int_as_float((int)(r1 >> 32));
            float w2 = __int_as_float((int)(r2 >> 32));
            float w3 = __int_as_float((int)(r3 >> 32));
#pragma unroll
            for (int i = 0; i < 4; ++i) {
                a0[i] += w0 * bf2f(h0[i]) + w1 * bf2f(h1[i]) + w2 * bf2f(h2[i]) +
                         w3 * bf2f(h3[i]);
                a1[i] += w0 * bf2f(h0[4 + i]) + w1 * bf2f(h1[4 + i]) +
                         w2 * bf2f(h2[4 + i]) + w3 * bf2f(h3[4 + i]);
            }
        }
        for (; jj < jend; ++jj) {
            long long r = sE[jj];
            short8 hb8 = *(const short8*)(hB + (((unsigned)(int)r) >> sh));
            float w = __int_as_float((int)(r >> 32));
#pragma unroll
            for (int i = 0; i < 4; ++i) {
                a0[i] += w * bf2f(hb8[i]);
                a1[i] += w * bf2f(hb8[4 + i]);
            }
        }
        if (jend > 0 && j < base + jend) j = base + jend;
    }

    if (!act) return;
    int v = v0 + n;
    float tk = temp[kidx];
    short8 ob;
#pragma unroll
    for (int i = 0; i < 4; ++i) { ob[i] = f2bf(a0[i]); ob[4 + i] = f2bf(a1[i]); }
    if (c < 4) *(short8*)(hn_lo + (size_t)v * 32 + c * 8) = ob;
    else       *(short8*)(hn_hi + (size_t)v * 8) = ob;
    float* pt = TH + (size_t)v * N_CLS + c * 8;
    f4_t t0v = *(const f4_t*)pt;
    f4_t t1v = *(((const f4_t*)pt) + 1);
    t0v += tk * a0;
    t1v += tk * a1;
    *(f4_t*)pt = t0v;
    *(((f4_t*)pt) + 1) = t1v;
}

// ---------------------------------------------------------------- log_softmax
__global__ __launch_bounds__(256) void lsm_kernel(float* __restrict__ out) {
    int wid = (blockIdx.x * 256 + threadIdx.x) >> 6;
    int lane = threadIdx.x & 63;
    if (wid >= N_NODES) return;
    float x = (lane < N_CLS) ? out[wid * N_CLS + lane] : -INFINITY;
    float m = x;
#pragma unroll
    for (int o = 32; o > 0; o >>= 1) m = fmaxf(m, __shfl_xor(m, o, 64));
    float e = (lane < N_CLS) ? expf(x - m) : 0.f;
    float s = e;
#pragma unroll
    for (int o = 32; o > 0; o >>= 1) s += __shfl_xor(s, o, 64);
    float r = x - m - logf(s);
    if (lane < N_CLS) out[wid * N_CLS + lane] = r;
}

// ---------------------------------------------------------------- launch

extern "C" void kernel_launch(void* const* d_in, const int* in_sizes, int n_in,
                              void* d_out, int out_size, void* d_ws, size_t ws_size,
                              hipStream_t stream) {
    const float* feat = (const float*)d_in[0];
    const float* W1   = (const float*)d_in[1];
    const float* b1   = (const float*)d_in[2];
    const float* W2   = (const float*)d_in[3];
    const float* b2   = (const float*)d_in[4];
    const float* temp = (const float*)d_in[5];
    const int*   src  = (const int*)d_in[6];
    const int*   dst  = (const int*)d_in[7];
    float* out = (float*)d_out;

    // workspace layout (bytes). degp region reused for W1T/W2T after scan_write.
    char* ws = (char*)d_ws;
    int*   degp    = (int*)(ws + 0);          // 3,200,000 B (dead after scan_write)
    short* W1T     = (short*)(ws + 0);        //   262,144 B (overlaps degp)
    short* W2T     = (short*)(ws + 262144);   //    32,768 B (overlaps degp)
    float* dnorm   = (float*)(ws + 3200000);  //   400,000 B
    int*   rowptrp = (int*)(ws + 3600000);    // 3,200,004 B
    int*   cursor  = (int*)(ws + 6800016);    // 3,200,000 B
    int2*  epair   = (int2*)(ws + 10000016);  // 13,600,000 B
    short* h0_lo   = (short*)(ws + 23600016); //  6,400,000 B (bf16 [N][32])
    short* h0_hi   = (short*)(ws + 30000016); //  1,600,000 B (bf16 [N][8])
    short* h1_lo   = (short*)(ws + 31600016); //  6,400,000 B
    short* h1_hi   = (short*)(ws + 38000016); //  1,600,000 B
    int*   blocksum = (int*)(ws + 39600016);  //     3,128 B
    int*   blockoff = (int*)(ws + 39603152);  //     3,128 B  -> end 39,606,280

    init_degp_kernel<<<(NPN + 255) / 256, 256, 0, stream>>>(degp);
    count_dst_kernel<<<(N_EDGES + 255) / 256, 256, 0, stream>>>(src, dst, degp);
    rsqrt_deg_kernel<<<(N_NODES + 255) / 256, 256, 0, stream>>>(degp, dnorm);
    scan_partial_kernel<<<SCANB, 1024, 0, stream>>>(degp, blocksum);
    scan_blocks_kernel<<<1, 1024, 0, stream>>>(blocksum, blockoff);
    scan_write_kernel<<<SCANB, 1024, 0, stream>>>(degp, blockoff, rowptrp, cursor);
    cvt_w1_kernel<<<512, 256, 0, stream>>>(W1, W1T);
    cvt_w2_kernel<<<64, 256, 0, stream>>>(W2, W2T);
    scatter_edges_kernel<<<(N_EDGES + 255) / 256, 256, 0, stream>>>(src, dst, dnorm, cursor,
                                                                    epair);
    scatter_self_kernel<<<(N_NODES + 255) / 256, 256, 0, stream>>>(dnorm, cursor, epair);

    mlp_kernel<<<(N_NODES + 63) / 64, 256, 0, stream>>>(feat, W1T, b1, W2T, b2, temp,
                                                        h0_lo, h0_hi, out);

    short* hcl = h0_lo; short* hch = h0_hi;
    short* hnl = h1_lo; short* hnh = h1_hi;
    for (int k = 0; k < K_HOPS; ++k) {
        prop_kernel<<<PGRID, 256, 0, stream>>>(hcl, hch, hnl, hnh, rowptrp, epair,
                                               out, temp, k + 1);
        short* t1 = hcl; hcl = hnl; hnl = t1;
        short* t2 = hch; hch = hnh; hnh = t2;
    }

    lsm_kernel<<<(N_NODES / 4), 256, 0, stream>>>(out);
}

// Round 6
// 935.157 us; speedup vs baseline: 1.0012x; 1.0012x over previous
//
#include <hip/hip_runtime.h>
#include <math.h>
#include <stdint.h>

#define N_NODES 100000
#define N_FEAT  512
#define HIDDEN  256
#define N_CLS   40
#define N_EDGES 1600000
#define K_HOPS  10

#define NPART   8                    // src partitions for L2-locality edge ordering
#define PSZ     12500                // nodes per src-part
#define NPN     (NPART * N_NODES)    // 800000 virtual CSR rows (dst, src_part)
#define SCANB   782                  // ceil((NPN+1)/1024)
#define HROW    40                   // h row: 40 bf16 = 80 B (16B-aligned)

#define PB      51                   // nodes per prop block (255 active threads * 5)
#define PGRID   ((N_NODES + PB - 1) / PB)   // 1961
#define ECAP    2048                 // LDS epair slots (block avg ~870)

typedef __attribute__((ext_vector_type(8))) short short8;   // 8 bf16
typedef __attribute__((ext_vector_type(4))) float f4_t;

__device__ __forceinline__ short f2bf(float f) {
    union { float f; unsigned u; } x; x.f = f;
    unsigned r = x.u + 0x7fffu + ((x.u >> 16) & 1u);  // RNE
    return (short)(r >> 16);
}

__device__ __forceinline__ float bf2f(short b) {
    union { unsigned u; float f; } x;
    x.u = ((unsigned)(unsigned short)b) << 16;
    return x.f;
}

// packed f32x2 -> bf16x2 (RNE), single HW instr; no builtin on gfx950
__device__ __forceinline__ unsigned cvtpk(float lo, float hi) {
    unsigned r;
    asm("v_cvt_pk_bf16_f32 %0, %1, %2" : "=v"(r) : "v"(lo), "v"(hi));
    return r;
}

// ---------------------------------------------------------------- prep kernels

__global__ __launch_bounds__(256) void init_degp_kernel(int* __restrict__ degp) {
    int idx = blockIdx.x * 256 + threadIdx.x;
    if (idx < NPN) {
        int v = idx >> 3, p = idx & 7;
        degp[idx] = (p == v / PSZ) ? 1 : 0;
    }
}

__global__ __launch_bounds__(256) void count_dst_kernel(const int* __restrict__ src,
                                                        const int* __restrict__ dst,
                                                        int* __restrict__ degp) {
    int e = blockIdx.x * 256 + threadIdx.x;
    if (e < N_EDGES) atomicAdd(&degp[dst[e] * NPART + src[e] / PSZ], 1);
}

__global__ __launch_bounds__(256) void rsqrt_deg_kernel(const int* __restrict__ degp,
                                                        float* __restrict__ d) {
    int v = blockIdx.x * 256 + threadIdx.x;
    if (v < N_NODES) {
        int s = 0;
#pragma unroll
        for (int p = 0; p < NPART; ++p) s += degp[v * NPART + p];
        d[v] = rsqrtf((float)s);
    }
}

// ---- 3-phase device-wide exclusive scan of degp -> rowptrp/cursor

__global__ __launch_bounds__(1024) void scan_partial_kernel(const int* __restrict__ degp,
                                                            int* __restrict__ blocksum) {
    __shared__ int s[1024];
    int t = threadIdx.x;
    int idx = blockIdx.x * 1024 + t;
    s[t] = (idx < NPN) ? degp[idx] : 0;
    __syncthreads();
#pragma unroll
    for (int off = 512; off > 0; off >>= 1) {
        if (t < off) s[t] += s[t + off];
        __syncthreads();
    }
    if (t == 0) blocksum[blockIdx.x] = s[0];
}

__global__ __launch_bounds__(1024) void scan_blocks_kernel(const int* __restrict__ blocksum,
                                                           int* __restrict__ blockoff) {
    __shared__ int s[1024];
    int t = threadIdx.x;
    int v = (t < SCANB) ? blocksum[t] : 0;
    s[t] = v;
    __syncthreads();
#pragma unroll
    for (int off = 1; off < 1024; off <<= 1) {
        int add = (t >= off) ? s[t - off] : 0;
        __syncthreads();
        s[t] += add;
        __syncthreads();
    }
    if (t < SCANB) blockoff[t] = s[t] - v;  // exclusive
}

__global__ __launch_bounds__(1024) void scan_write_kernel(const int* __restrict__ degp,
                                                          const int* __restrict__ blockoff,
                                                          int* __restrict__ rowptrp,
                                                          int* __restrict__ cursor) {
    __shared__ int s[1024];
    int t = threadIdx.x;
    int idx = blockIdx.x * 1024 + t;
    int v = (idx < NPN) ? degp[idx] : 0;
    s[t] = v;
    __syncthreads();
#pragma unroll
    for (int off = 1; off < 1024; off <<= 1) {
        int add = (t >= off) ? s[t - off] : 0;
        __syncthreads();
        s[t] += add;
        __syncthreads();
    }
    int pre = s[t] - v + blockoff[blockIdx.x];  // exclusive prefix
    if (idx <= NPN) rowptrp[idx] = pre;
    if (idx < NPN) cursor[idx] = pre;
}

// epair.x holds PRE-SCALED byte offset (u*80) so prop needs no multiply
__global__ __launch_bounds__(256) void scatter_edges_kernel(const int* __restrict__ src,
                                                            const int* __restrict__ dst,
                                                            const float* __restrict__ d,
                                                            int* __restrict__ cursor,
                                                            int2* __restrict__ epair) {
    int e = blockIdx.x * 256 + threadIdx.x;
    if (e >= N_EDGES) return;
    int u = src[e], v = dst[e];
    int pos = atomicAdd(&cursor[v * NPART + u / PSZ], 1);
    int2 p;
    p.x = u * 80;
    p.y = __float_as_int(d[u] * d[v]);
    epair[pos] = p;
}

__global__ __launch_bounds__(256) void scatter_self_kernel(const float* __restrict__ d,
                                                           int* __restrict__ cursor,
                                                           int2* __restrict__ epair) {
    int v = blockIdx.x * 256 + threadIdx.x;
    if (v >= N_NODES) return;
    int pos = atomicAdd(&cursor[v * NPART + v / PSZ], 1);
    float dv = d[v];
    int2 p;
    p.x = v * 80;
    p.y = __float_as_int(dv * dv);
    epair[pos] = p;
}

// W1 [512][256] f32 -> W1T [256][512] bf16 (col-major: per-col k contiguous)
__global__ __launch_bounds__(256) void cvt_w1_kernel(const float* __restrict__ W1,
                                                     short* __restrict__ W1T) {
    int lin = blockIdx.x * 256 + threadIdx.x;  // 131072
    int k = lin >> 8, n = lin & 255;
    W1T[n * 512 + k] = f2bf(W1[lin]);
}

// W2 [256][40] f32 -> W2T [64][256] bf16, rows >=40 zero
__global__ __launch_bounds__(256) void cvt_w2_kernel(const float* __restrict__ W2,
                                                     short* __restrict__ W2T) {
    int lin = blockIdx.x * 256 + threadIdx.x;  // 16384
    int n = lin >> 8, k = lin & 255;
    W2T[lin] = (n < N_CLS) ? f2bf(W2[k * N_CLS + n]) : (short)0;
}

// ---------------------------------------------------------------- fused MLP (MFMA)
// Phase A is BARRIER-FREE: each wave computes an independent 32-row x 128-col
// tile of h1 = relu(feat@W1+b1) with direct global loads (A-frags 32B/lane
// contiguous from feat; B-frags from L2-hot W1T). Full-unroll K-loop (16 kt,
// compile-time indices), depth-1 A prefetch. The 4 waves (2 row-tiles x 2
// col-halves) join ONCE at sH, then phase B + epilogue = proven r3 code.
// LDS = 33.8 KB union -> 4 blocks/CU.
__global__ __launch_bounds__(256, 3) void mlp_kernel(const float* __restrict__ feat,
                                                     const short* __restrict__ W1T,
                                                     const float* __restrict__ b1,
                                                     const short* __restrict__ W2T,
                                                     const float* __restrict__ b2,
                                                     const float* __restrict__ temp,
                                                     short* __restrict__ h,
                                                     float* __restrict__ TH) {
    __shared__ union {
        short sH[64][264];                                 // 33792 B (phase A out / B in)
        struct { short Ho[64][40]; float To[64][40]; } o;  // 15360 B (epilogue)
    } S;

    const int tid = threadIdx.x;
    const int rbase = blockIdx.x * 64;
    const int lane = tid & 63;
    const int wv = tid >> 6;       // wave 0..3
    const int quad = lane >> 4;    // 0..3
    const int l15 = lane & 15;

    // ---- phase A: wave (rt, ch) -> rows [wrbase, wrbase+32), cols [ch*128, +128)
    const int rt = wv >> 1;        // row-tile 0/1
    const int ch = wv & 1;         // col-half 0/1
    const int wrbase = rbase + rt * 32;

    int gr0 = wrbase + l15;       if (gr0 >= N_NODES) gr0 = N_NODES - 1;
    int gr1 = wrbase + 16 + l15;  if (gr1 >= N_NODES) gr1 = N_NODES - 1;
    const float* fp0 = feat + (size_t)gr0 * N_FEAT + quad * 8;
    const float* fp1 = feat + (size_t)gr1 * N_FEAT + quad * 8;
    const short* wb  = W1T + (size_t)(ch * 128 + l15) * 512 + quad * 8;

    f4_t acc[2][8];
#pragma unroll
    for (int m = 0; m < 2; ++m)
#pragma unroll
        for (int n = 0; n < 8; ++n) acc[m][n] = (f4_t)0.f;

    f4_t nA00, nA01, nA10, nA11;   // depth-1 A prefetch (8 f32 per row-frag)
    nA00 = *(const f4_t*)(fp0);     nA01 = *(const f4_t*)(fp0 + 4);
    nA10 = *(const f4_t*)(fp1);     nA11 = *(const f4_t*)(fp1 + 4);

#pragma unroll
    for (int kt = 0; kt < 16; ++kt) {
        f4_t a00 = nA00, a01 = nA01, a10 = nA10, a11 = nA11;
        if (kt < 15) {
            const float* p0 = fp0 + (kt + 1) * 32;
            const float* p1 = fp1 + (kt + 1) * 32;
            nA00 = *(const f4_t*)(p0); nA01 = *(const f4_t*)(p0 + 4);
            nA10 = *(const f4_t*)(p1); nA11 = *(const f4_t*)(p1 + 4);
        }
        short8 af0, af1;
        {
            union { unsigned u[4]; short8 s; } x;
            x.u[0] = cvtpk(a00[0], a00[1]); x.u[1] = cvtpk(a00[2], a00[3]);
            x.u[2] = cvtpk(a01[0], a01[1]); x.u[3] = cvtpk(a01[2], a01[3]);
            af0 = x.s;
            x.u[0] = cvtpk(a10[0], a10[1]); x.u[1] = cvtpk(a10[2], a10[3]);
            x.u[2] = cvtpk(a11[0], a11[1]); x.u[3] = cvtpk(a11[2], a11[3]);
            af1 = x.s;
        }
#pragma unroll
        for (int n = 0; n < 8; ++n) {
            short8 bf = *(const short8*)(wb + (size_t)n * 16 * 512 + kt * 32);
            acc[0][n] = __builtin_amdgcn_mfma_f32_16x16x32_bf16(af0, bf, acc[0][n], 0, 0, 0);
            acc[1][n] = __builtin_amdgcn_mfma_f32_16x16x32_bf16(af1, bf, acc[1][n], 0, 0, 0);
        }
    }

    // bias + relu -> sH (wave-disjoint region; join once)
#pragma unroll
    for (int n = 0; n < 8; ++n) {
        int col = ch * 128 + n * 16 + l15;
        float bb = b1[col];
#pragma unroll
        for (int m = 0; m < 2; ++m)
#pragma unroll
            for (int r = 0; r < 4; ++r) {
                float v = acc[m][n][r] + bb;
                S.sH[rt * 32 + m * 16 + quad * 4 + r][col] = f2bf(v > 0.f ? v : 0.f);
            }
    }
    __syncthreads();

    // ---- phase B: out = sH @ W2 + b2 ; W2 fragments from L1/L2 (32 KB, hot)
    f4_t accB[3];
#pragma unroll
    for (int n = 0; n < 3; ++n) accB[n] = (f4_t)0.f;
#pragma unroll
    for (int kk = 0; kk < 256; kk += 32) {
        short8 a = *(const short8*)&S.sH[wv * 16 + l15][kk + quad * 8];
#pragma unroll
        for (int n = 0; n < 3; ++n) {
            short8 b = *(const short8*)(W2T + (n * 16 + l15) * 256 + kk + quad * 8);
            accB[n] = __builtin_amdgcn_mfma_f32_16x16x32_bf16(a, b, accB[n], 0, 0, 0);
        }
    }
    __syncthreads();  // sH reads done -> epilogue staging may overwrite

    float t0 = temp[0];
#pragma unroll
    for (int n = 0; n < 3; ++n) {
        int col = n * 16 + l15;
        if (col < N_CLS) {
            float bb = b2[col];
#pragma unroll
            for (int r = 0; r < 4; ++r) {
                int row = wv * 16 + quad * 4 + r;
                float v = accB[n][r] + bb;
                S.o.Ho[row][col] = f2bf(v);
                S.o.To[row][col] = t0 * v;
            }
        }
    }
    __syncthreads();

    // coalesced 16B writes of h (bf16 [N][40]) and TH (f32 [N][40])
    int rows = N_NODES - rbase; if (rows > 64) rows = 64;
    int nh = rows * 5;    // short8 chunks
    for (int i = tid; i < nh; i += 256)
        *(short8*)(h + (size_t)rbase * HROW + i * 8) =
            *(const short8*)((const short*)&S.o.Ho[0][0] + i * 8);
    int nt = rows * 10;   // f4 chunks
    for (int i = tid; i < nt; i += 256)
        *(f4_t*)(TH + (size_t)rbase * N_CLS + i * 4) =
            *(const f4_t*)((const float*)&S.o.To[0][0] + i * 4);
}

// ---------------------------------------------------------------- propagation
// (verbatim round-3-proven version, 852us total)
// Block = 51 nodes x 5 lanes (255 active). Block's epair slice staged into LDS
// (coalesced, dedups the 5x redundant reads, removes global latency from the
// address chain). Gathers 4-deep. Edges part-ordered for L2 locality.
__global__ __launch_bounds__(256, 8) void prop_kernel(const short* __restrict__ h,
                                                      short* __restrict__ hn,
                                                      const int* __restrict__ rowptrp,
                                                      const int2* __restrict__ epair,
                                                      float* __restrict__ TH,
                                                      const float* __restrict__ temp,
                                                      int kidx) {
    __shared__ long long sE[ECAP];
    __shared__ int sRP[64];

    const int t = threadIdx.x;
    const int v0 = blockIdx.x * PB;
    int nmax = N_NODES - v0; if (nmax > PB) nmax = PB;
    if (t <= nmax) sRP[t] = rowptrp[(v0 + t) * NPART];
    __syncthreads();
    const int S0 = sRP[0];
    const int count = sRP[nmax] - S0;

    const int n = t / 5;
    const int c = t - n * 5;
    const bool act = (n < nmax) && (t < 255);
    const int js = act ? (sRP[n] - S0) : 0;
    const int je = act ? (sRP[n + 1] - S0) : 0;
    const char* hB = (const char*)h + c * 16;

    f4_t a0 = (f4_t)0.f, a1 = (f4_t)0.f;
    int j = js;
    for (int base = 0; base < count; base += ECAP) {
        int lim = count - base; if (lim > ECAP) lim = ECAP;
        __syncthreads();
        for (int i = t; i < lim; i += 256)
            sE[i] = *(const long long*)(epair + (size_t)(S0 + base + i));
        __syncthreads();
        int jend = je - base; if (jend > lim) jend = lim;
        int jj = j - base;
        for (; jj + 4 <= jend; jj += 4) {
            long long r0 = sE[jj], r1 = sE[jj + 1], r2 = sE[jj + 2], r3 = sE[jj + 3];
            short8 h0 = *(const short8*)(hB + (unsigned)(int)r0);
            short8 h1 = *(const short8*)(hB + (unsigned)(int)r1);
            short8 h2 = *(const short8*)(hB + (unsigned)(int)r2);
            short8 h3 = *(const short8*)(hB + (unsigned)(int)r3);
            float w0 = __int_as_float((int)(r0 >> 32));
            float w1 = __int_as_float((int)(r1 >> 32));
            float w2 = __int_as_float((int)(r2 >> 32));
            float w3 = __int_as_float((int)(r3 >> 32));
#pragma unroll
            for (int i = 0; i < 4; ++i) {
                a0[i] += w0 * bf2f(h0[i]) + w1 * bf2f(h1[i]) + w2 * bf2f(h2[i]) +
                         w3 * bf2f(h3[i]);
                a1[i] += w0 * bf2f(h0[4 + i]) + w1 * bf2f(h1[4 + i]) +
                         w2 * bf2f(h2[4 + i]) + w3 * bf2f(h3[4 + i]);
            }
        }
        for (; jj < jend; ++jj) {
            long long r = sE[jj];
            short8 hb8 = *(const short8*)(hB + (unsigned)(int)r);
            float w = __int_as_float((int)(r >> 32));
#pragma unroll
            for (int i = 0; i < 4; ++i) {
                a0[i] += w * bf2f(hb8[i]);
                a1[i] += w * bf2f(hb8[4 + i]);
            }
        }
        if (jend > 0 && j < base + jend) j = base + jend;
    }

    if (!act) return;
    int v = v0 + n;
    float tk = temp[kidx];
    short8 ob;
#pragma unroll
    for (int i = 0; i < 4; ++i) { ob[i] = f2bf(a0[i]); ob[4 + i] = f2bf(a1[i]); }
    *(short8*)(hn + (size_t)v * HROW + c * 8) = ob;
    float* pt = TH + (size_t)v * N_CLS + c * 8;
    f4_t t0v = *(const f4_t*)pt;
    f4_t t1v = *(((const f4_t*)pt) + 1);
    t0v += tk * a0;
    t1v += tk * a1;
    *(f4_t*)pt = t0v;
    *(((f4_t*)pt) + 1) = t1v;
}

// ---------------------------------------------------------------- log_softmax
__global__ __launch_bounds__(256) void lsm_kernel(float* __restrict__ out) {
    int wid = (blockIdx.x * 256 + threadIdx.x) >> 6;
    int lane = threadIdx.x & 63;
    if (wid >= N_NODES) return;
    float x = (lane < N_CLS) ? out[wid * N_CLS + lane] : -INFINITY;
    float m = x;
#pragma unroll
    for (int o = 32; o > 0; o >>= 1) m = fmaxf(m, __shfl_xor(m, o, 64));
    float e = (lane < N_CLS) ? expf(x - m) : 0.f;
    float s = e;
#pragma unroll
    for (int o = 32; o > 0; o >>= 1) s += __shfl_xor(s, o, 64);
    float r = x - m - logf(s);
    if (lane < N_CLS) out[wid * N_CLS + lane] = r;
}

// ---------------------------------------------------------------- launch

extern "C" void kernel_launch(void* const* d_in, const int* in_sizes, int n_in,
                              void* d_out, int out_size, void* d_ws, size_t ws_size,
                              hipStream_t stream) {
    const float* feat = (const float*)d_in[0];
    const float* W1   = (const float*)d_in[1];
    const float* b1   = (const float*)d_in[2];
    const float* W2   = (const float*)d_in[3];
    const float* b2   = (const float*)d_in[4];
    const float* temp = (const float*)d_in[5];
    const int*   src  = (const int*)d_in[6];
    const int*   dst  = (const int*)d_in[7];
    float* out = (float*)d_out;

    // workspace layout (bytes). degp region reused for W1T/W2T after scan_write.
    char* ws = (char*)d_ws;
    int*   degp    = (int*)(ws + 0);          // 3,200,000 B (dead after scan_write)
    short* W1T     = (short*)(ws + 0);        //   262,144 B (overlaps degp)
    short* W2T     = (short*)(ws + 262144);   //    32,768 B (overlaps degp)
    float* dnorm   = (float*)(ws + 3200000);  //   400,000 B
    int*   rowptrp = (int*)(ws + 3600000);    // 3,200,004 B
    int*   cursor  = (int*)(ws + 6800016);    // 3,200,000 B
    int2*  epair   = (int2*)(ws + 10000016);  // 13,600,000 B
    short* h0      = (short*)(ws + 23600016); //  8,000,000 B (bf16, [N][40])
    short* h1      = (short*)(ws + 31600016); //  8,000,000 B
    int*   blocksum = (int*)(ws + 39600016);  //     3,128 B
    int*   blockoff = (int*)(ws + 39603152);  //     3,128 B  -> end 39,606,280

    init_degp_kernel<<<(NPN + 255) / 256, 256, 0, stream>>>(degp);
    count_dst_kernel<<<(N_EDGES + 255) / 256, 256, 0, stream>>>(src, dst, degp);
    rsqrt_deg_kernel<<<(N_NODES + 255) / 256, 256, 0, stream>>>(degp, dnorm);
    scan_partial_kernel<<<SCANB, 1024, 0, stream>>>(degp, blocksum);
    scan_blocks_kernel<<<1, 1024, 0, stream>>>(blocksum, blockoff);
    scan_write_kernel<<<SCANB, 1024, 0, stream>>>(degp, blockoff, rowptrp, cursor);
    cvt_w1_kernel<<<512, 256, 0, stream>>>(W1, W1T);
    cvt_w2_kernel<<<64, 256, 0, stream>>>(W2, W2T);
    scatter_edges_kernel<<<(N_EDGES + 255) / 256, 256, 0, stream>>>(src, dst, dnorm, cursor,
                                                                    epair);
    scatter_self_kernel<<<(N_NODES + 255) / 256, 256, 0, stream>>>(dnorm, cursor, epair);

    mlp_kernel<<<(N_NODES + 63) / 64, 256, 0, stream>>>(feat, W1T, b1, W2T, b2, temp, h0, out);

    short* hc = h0;
    short* hn = h1;
    for (int k = 0; k < K_HOPS; ++k) {
        prop_kernel<<<PGRID, 256, 0, stream>>>(hc, hn, rowptrp, epair, out, temp, k + 1);
        short* t = hc; hc = hn; hn = t;
    }

    lsm_kernel<<<(N_NODES / 4), 256, 0, stream>>>(out);
}

// Round 7
// 844.151 us; speedup vs baseline: 1.1091x; 1.1078x over previous
//
#include <hip/hip_runtime.h>
#include <math.h>
#include <stdint.h>

#define N_NODES 100000
#define N_FEAT  512
#define HIDDEN  256
#define N_CLS   40
#define N_EDGES 1600000
#define K_HOPS  10

#define NPART   8                    // src partitions for L2-locality edge ordering
#define PSZ     12500                // nodes per src-part
#define NPN     (NPART * N_NODES)    // 800000 virtual CSR rows (dst, src_part)
#define SCANB   782                  // ceil((NPN+1)/1024)
#define HPAD    64                   // padded h row: 64 bf16 = 128 B = exactly 1 L2 line

#define PB      51                   // nodes per prop block (255 active threads * 5)
#define PGRID   ((N_NODES + PB - 1) / PB)   // 1961
#define ECAP    2048                 // LDS epair slots (block avg ~870)

typedef __attribute__((ext_vector_type(8))) short short8;   // 8 bf16
typedef __attribute__((ext_vector_type(4))) float f4_t;

__device__ __forceinline__ short f2bf(float f) {
    union { float f; unsigned u; } x; x.f = f;
    unsigned r = x.u + 0x7fffu + ((x.u >> 16) & 1u);  // RNE
    return (short)(r >> 16);
}

__device__ __forceinline__ float bf2f(short b) {
    union { unsigned u; float f; } x;
    x.u = ((unsigned)(unsigned short)b) << 16;
    return x.f;
}

// packed f32x2 -> bf16x2 (RNE), single HW instr; no builtin on gfx950
__device__ __forceinline__ unsigned cvtpk(float lo, float hi) {
    unsigned r;
    asm("v_cvt_pk_bf16_f32 %0, %1, %2" : "=v"(r) : "v"(lo), "v"(hi));
    return r;
}

// ---------------------------------------------------------------- prep kernels

__global__ __launch_bounds__(256) void init_degp_kernel(int* __restrict__ degp) {
    int idx = blockIdx.x * 256 + threadIdx.x;
    if (idx < NPN) {
        int v = idx >> 3, p = idx & 7;
        degp[idx] = (p == v / PSZ) ? 1 : 0;
    }
}

__global__ __launch_bounds__(256) void count_dst_kernel(const int* __restrict__ src,
                                                        const int* __restrict__ dst,
                                                        int* __restrict__ degp) {
    int e = blockIdx.x * 256 + threadIdx.x;
    if (e < N_EDGES) atomicAdd(&degp[dst[e] * NPART + src[e] / PSZ], 1);
}

__global__ __launch_bounds__(256) void rsqrt_deg_kernel(const int* __restrict__ degp,
                                                        float* __restrict__ d) {
    int v = blockIdx.x * 256 + threadIdx.x;
    if (v < N_NODES) {
        int s = 0;
#pragma unroll
        for (int p = 0; p < NPART; ++p) s += degp[v * NPART + p];
        d[v] = rsqrtf((float)s);
    }
}

// ---- 3-phase device-wide exclusive scan of degp -> rowptrp/cursor

__global__ __launch_bounds__(1024) void scan_partial_kernel(const int* __restrict__ degp,
                                                            int* __restrict__ blocksum) {
    __shared__ int s[1024];
    int t = threadIdx.x;
    int idx = blockIdx.x * 1024 + t;
    s[t] = (idx < NPN) ? degp[idx] : 0;
    __syncthreads();
#pragma unroll
    for (int off = 512; off > 0; off >>= 1) {
        if (t < off) s[t] += s[t + off];
        __syncthreads();
    }
    if (t == 0) blocksum[blockIdx.x] = s[0];
}

__global__ __launch_bounds__(1024) void scan_blocks_kernel(const int* __restrict__ blocksum,
                                                           int* __restrict__ blockoff) {
    __shared__ int s[1024];
    int t = threadIdx.x;
    int v = (t < SCANB) ? blocksum[t] : 0;
    s[t] = v;
    __syncthreads();
#pragma unroll
    for (int off = 1; off < 1024; off <<= 1) {
        int add = (t >= off) ? s[t - off] : 0;
        __syncthreads();
        s[t] += add;
        __syncthreads();
    }
    if (t < SCANB) blockoff[t] = s[t] - v;  // exclusive
}

__global__ __launch_bounds__(1024) void scan_write_kernel(const int* __restrict__ degp,
                                                          const int* __restrict__ blockoff,
                                                          int* __restrict__ rowptrp,
                                                          int* __restrict__ cursor) {
    __shared__ int s[1024];
    int t = threadIdx.x;
    int idx = blockIdx.x * 1024 + t;
    int v = (idx < NPN) ? degp[idx] : 0;
    s[t] = v;
    __syncthreads();
#pragma unroll
    for (int off = 1; off < 1024; off <<= 1) {
        int add = (t >= off) ? s[t - off] : 0;
        __syncthreads();
        s[t] += add;
        __syncthreads();
    }
    int pre = s[t] - v + blockoff[blockIdx.x];  // exclusive prefix
    if (idx <= NPN) rowptrp[idx] = pre;
    if (idx < NPN) cursor[idx] = pre;
}

// epair.x holds PRE-SCALED byte offset (u*128) so prop needs no multiply
__global__ __launch_bounds__(256) void scatter_edges_kernel(const int* __restrict__ src,
                                                            const int* __restrict__ dst,
                                                            const float* __restrict__ d,
                                                            int* __restrict__ cursor,
                                                            int2* __restrict__ epair) {
    int e = blockIdx.x * 256 + threadIdx.x;
    if (e >= N_EDGES) return;
    int u = src[e], v = dst[e];
    int pos = atomicAdd(&cursor[v * NPART + u / PSZ], 1);
    int2 p;
    p.x = u * 128;
    p.y = __float_as_int(d[u] * d[v]);
    epair[pos] = p;
}

__global__ __launch_bounds__(256) void scatter_self_kernel(const float* __restrict__ d,
                                                           int* __restrict__ cursor,
                                                           int2* __restrict__ epair) {
    int v = blockIdx.x * 256 + threadIdx.x;
    if (v >= N_NODES) return;
    int pos = atomicAdd(&cursor[v * NPART + v / PSZ], 1);
    float dv = d[v];
    int2 p;
    p.x = v * 128;
    p.y = __float_as_int(dv * dv);
    epair[pos] = p;
}

// W1 [512][256] f32 -> W1T [256][512] bf16 (col-major: per-col k contiguous)
__global__ __launch_bounds__(256) void cvt_w1_kernel(const float* __restrict__ W1,
                                                     short* __restrict__ W1T) {
    int lin = blockIdx.x * 256 + threadIdx.x;  // 131072
    int k = lin >> 8, n = lin & 255;
    W1T[n * 512 + k] = f2bf(W1[lin]);
}

// W2 [256][40] f32 -> W2T [64][256] bf16, rows >=40 zero
__global__ __launch_bounds__(256) void cvt_w2_kernel(const float* __restrict__ W2,
                                                     short* __restrict__ W2T) {
    int lin = blockIdx.x * 256 + threadIdx.x;  // 16384
    int n = lin >> 8, k = lin & 255;
    W2T[lin] = (n < N_CLS) ? f2bf(W2[k * N_CLS + n]) : (short)0;
}

// ---------------------------------------------------------------- fused MLP (MFMA)
// r5's best-measured variant (120.5us) verbatim; only the h epilogue target
// changed to padded [N][64] rows. Block = 256 thr (4 waves), 64 rows. bf16
// A-tile [64][72] (144B stride = clean 2-way banks), double-buffered, ONE raw
// s_barrier + lgkmcnt(0) per kt. feat tile and W1T fragments register-
// prefetched one kt ahead; vmcnt waits are compiler-counted, never drained.
__global__ __launch_bounds__(256) void mlp_kernel(const float* __restrict__ feat,
                                                  const short* __restrict__ W1T,
                                                  const float* __restrict__ b1,
                                                  const short* __restrict__ W2T,
                                                  const float* __restrict__ b2,
                                                  const float* __restrict__ temp,
                                                  short* __restrict__ h,
                                                  float* __restrict__ TH) {
    __shared__ union {
        short A[2][64][72];                                // 18432 B (K-loop)
        short sH[64][264];                                 // 33792 B (phase B in)
        struct { short Ho[64][40]; float To[64][40]; } o;  // 15360 B (epilogue)
    } S;

    const int tid = threadIdx.x;
    const int rbase = blockIdx.x * 64;
    const int lane = tid & 63;
    const int wv = tid >> 6;       // wave 0..3
    const int quad = lane >> 4;    // 0..3
    const int l15 = lane & 15;

    f4_t acc[4][4];
#pragma unroll
    for (int m = 0; m < 4; ++m)
#pragma unroll
        for (int n = 0; n < 4; ++n) acc[m][n] = (f4_t)0.f;

    // staging: thread owns row tid>>2, float-quarter tid&3 (16 floats / kt)
    const int srow = tid >> 2;
    const int scol = (tid & 3) * 16;
    int growc = rbase + srow;
    if (growc >= N_NODES) growc = N_NODES - 1;   // clamp; masked in epilogue
    const float* fp = feat + (size_t)growc * N_FEAT + scol;

    f4_t fR0, fR1, fR2, fR3;   // feat prefetch (one kt ahead)
    short8 bR[8];              // W1T fragment prefetch (one kt ahead)

#define LOADF(KT)                                                   \
    { const f4_t* p_ = (const f4_t*)(fp + (KT) * 64);               \
      fR0 = p_[0]; fR1 = p_[1]; fR2 = p_[2]; fR3 = p_[3]; }

#define LOADB(KT)                                                   \
    { const short* wb_ = W1T + (KT) * 64;                           \
      _Pragma("unroll")                                             \
      for (int kk2 = 0; kk2 < 2; ++kk2)                             \
          _Pragma("unroll")                                         \
          for (int n = 0; n < 4; ++n)                               \
              bR[kk2 * 4 + n] = *(const short8*)(                   \
                  wb_ + (wv * 64 + n * 16 + l15) * 512 + kk2 * 32 + quad * 8); }

#define CVTWR(BUF)                                                  \
    { union { unsigned u[4]; short8 s; } xlo_, xhi_;                \
      xlo_.u[0] = cvtpk(fR0[0], fR0[1]); xlo_.u[1] = cvtpk(fR0[2], fR0[3]); \
      xlo_.u[2] = cvtpk(fR1[0], fR1[1]); xlo_.u[3] = cvtpk(fR1[2], fR1[3]); \
      xhi_.u[0] = cvtpk(fR2[0], fR2[1]); xhi_.u[1] = cvtpk(fR2[2], fR2[3]); \
      xhi_.u[2] = cvtpk(fR3[0], fR3[1]); xhi_.u[3] = cvtpk(fR3[2], fR3[3]); \
      short8* dp_ = (short8*)&S.A[BUF][srow][scol];                 \
      dp_[0] = xlo_.s; dp_[1] = xhi_.s; }

#define BARRIER()                                                   \
    asm volatile("s_waitcnt lgkmcnt(0)" ::: "memory");              \
    __builtin_amdgcn_s_barrier();                                   \
    __builtin_amdgcn_sched_barrier(0);

    // prologue: tile0 -> A[0]; bR <- kt0 frags; tile1 in regs
    LOADF(0);
    LOADB(0);
    CVTWR(0);      // waits fR (tile0); bR loads stay in flight
    LOADF(1);
    BARRIER();

#pragma unroll
    for (int kt = 0; kt < 8; ++kt) {
        const int cb = kt & 1;
        // MFMA on tile kt (A[cb] in LDS, bR in regs)
#pragma unroll
        for (int kk2 = 0; kk2 < 2; ++kk2) {
            short8 af[4];
#pragma unroll
            for (int m = 0; m < 4; ++m)
                af[m] = *(const short8*)&S.A[cb][m * 16 + l15][kk2 * 32 + quad * 8];
#pragma unroll
            for (int m = 0; m < 4; ++m)
#pragma unroll
                for (int n = 0; n < 4; ++n)
                    acc[m][n] = __builtin_amdgcn_mfma_f32_16x16x32_bf16(
                        af[m], bR[kk2 * 4 + n], acc[m][n], 0, 0, 0);
        }
        if (kt < 7) {
            LOADB(kt + 1);   // refill bR right after last use; lands under next kt
            CVTWR(cb ^ 1);   // tile kt+1 (regs loaded last iter) -> other LDS buf
        }
        if (kt < 6) LOADF(kt + 2);
        BARRIER();
    }
#undef LOADF
#undef LOADB
#undef CVTWR

    // bias + relu -> sH (A dead; all waves past final barrier)
#pragma unroll
    for (int n = 0; n < 4; ++n) {
        int col = wv * 64 + n * 16 + l15;
        float bb = b1[col];
#pragma unroll
        for (int m = 0; m < 4; ++m)
#pragma unroll
            for (int r = 0; r < 4; ++r) {
                float v = acc[m][n][r] + bb;
                S.sH[m * 16 + quad * 4 + r][col] = f2bf(v > 0.f ? v : 0.f);
            }
    }
    __syncthreads();

    // phase B: out = sH @ W2 + b2 ; W2 fragments from L1/L2 (32 KB, hot)
    f4_t accB[3];
#pragma unroll
    for (int n = 0; n < 3; ++n) accB[n] = (f4_t)0.f;
#pragma unroll
    for (int kk = 0; kk < 256; kk += 32) {
        short8 a = *(const short8*)&S.sH[wv * 16 + l15][kk + quad * 8];
#pragma unroll
        for (int n = 0; n < 3; ++n) {
            short8 b = *(const short8*)(W2T + (n * 16 + l15) * 256 + kk + quad * 8);
            accB[n] = __builtin_amdgcn_mfma_f32_16x16x32_bf16(a, b, accB[n], 0, 0, 0);
        }
    }
    __syncthreads();  // sH reads done -> epilogue staging may overwrite

    float t0 = temp[0];
#pragma unroll
    for (int n = 0; n < 3; ++n) {
        int col = n * 16 + l15;
        if (col < N_CLS) {
            float bb = b2[col];
#pragma unroll
            for (int r = 0; r < 4; ++r) {
                int row = wv * 16 + quad * 4 + r;
                float v = accB[n][r] + bb;
                S.o.Ho[row][col] = f2bf(v);
                S.o.To[row][col] = t0 * v;
            }
        }
    }
    __syncthreads();

    // coalesced 16B writes: h (bf16 [N][64] padded) and TH (f32 [N][40])
    int rows = N_NODES - rbase; if (rows > 64) rows = 64;
    int nh = rows * 5;    // short8 chunks (80B payload per 128B row)
    for (int i = tid; i < nh; i += 256) {
        int row = i / 5, part = i - row * 5;
        *(short8*)(h + (size_t)(rbase + row) * HPAD + part * 8) =
            *(const short8*)&S.o.Ho[row][part * 8];
    }
    int nt = rows * 10;   // f4 chunks
    for (int i = tid; i < nt; i += 256)
        *(f4_t*)(TH + (size_t)rbase * N_CLS + i * 4) =
            *(const f4_t*)((const float*)&S.o.To[0][0] + i * 4);
}

// ---------------------------------------------------------------- propagation
// r3-proven structure; h rows now 128B-padded so each edge-gather touches
// EXACTLY one L2 line (was ~1.6 at 80B rows -> ~40% less L2 line traffic).
// Block = 51 nodes x 5 lanes. epair slice staged in LDS (dedups 5x reads,
// removes global latency from the address chain). Edges part-ordered.
__global__ __launch_bounds__(256, 8) void prop_kernel(const short* __restrict__ h,
                                                      short* __restrict__ hn,
                                                      const int* __restrict__ rowptrp,
                                                      const int2* __restrict__ epair,
                                                      float* __restrict__ TH,
                                                      const float* __restrict__ temp,
                                                      int kidx) {
    __shared__ long long sE[ECAP];
    __shared__ int sRP[64];

    const int t = threadIdx.x;
    const int v0 = blockIdx.x * PB;
    int nmax = N_NODES - v0; if (nmax > PB) nmax = PB;
    if (t <= nmax) sRP[t] = rowptrp[(v0 + t) * NPART];
    __syncthreads();
    const int S0 = sRP[0];
    const int count = sRP[nmax] - S0;

    const int n = t / 5;
    const int c = t - n * 5;
    const bool act = (n < nmax) && (t < 255);
    const int js = act ? (sRP[n] - S0) : 0;
    const int je = act ? (sRP[n + 1] - S0) : 0;
    const char* hB = (const char*)h + c * 16;

    f4_t a0 = (f4_t)0.f, a1 = (f4_t)0.f;
    int j = js;
    for (int base = 0; base < count; base += ECAP) {
        int lim = count - base; if (lim > ECAP) lim = ECAP;
        __syncthreads();
        for (int i = t; i < lim; i += 256)
            sE[i] = *(const long long*)(epair + (size_t)(S0 + base + i));
        __syncthreads();
        int jend = je - base; if (jend > lim) jend = lim;
        int jj = j - base;
        for (; jj + 4 <= jend; jj += 4) {
            long long r0 = sE[jj], r1 = sE[jj + 1], r2 = sE[jj + 2], r3 = sE[jj + 3];
            short8 h0 = *(const short8*)(hB + (unsigned)(int)r0);
            short8 h1 = *(const short8*)(hB + (unsigned)(int)r1);
            short8 h2 = *(const short8*)(hB + (unsigned)(int)r2);
            short8 h3 = *(const short8*)(hB + (unsigned)(int)r3);
            float w0 = __int_as_float((int)(r0 >> 32));
            float w1 = __int_as_float((int)(r1 >> 32));
            float w2 = __int_as_float((int)(r2 >> 32));
            float w3 = __int_as_float((int)(r3 >> 32));
#pragma unroll
            for (int i = 0; i < 4; ++i) {
                a0[i] += w0 * bf2f(h0[i]) + w1 * bf2f(h1[i]) + w2 * bf2f(h2[i]) +
                         w3 * bf2f(h3[i]);
                a1[i] += w0 * bf2f(h0[4 + i]) + w1 * bf2f(h1[4 + i]) +
                         w2 * bf2f(h2[4 + i]) + w3 * bf2f(h3[4 + i]);
            }
        }
        for (; jj < jend; ++jj) {
            long long r = sE[jj];
            short8 hb8 = *(const short8*)(hB + (unsigned)(int)r);
            float w = __int_as_float((int)(r >> 32));
#pragma unroll
            for (int i = 0; i < 4; ++i) {
                a0[i] += w * bf2f(hb8[i]);
                a1[i] += w * bf2f(hb8[4 + i]);
            }
        }
        if (jend > 0 && j < base + jend) j = base + jend;
    }

    if (!act) return;
    int v = v0 + n;
    float tk = temp[kidx];
    short8 ob;
#pragma unroll
    for (int i = 0; i < 4; ++i) { ob[i] = f2bf(a0[i]); ob[4 + i] = f2bf(a1[i]); }
    *(short8*)(hn + (size_t)v * HPAD + c * 8) = ob;
    float* pt = TH + (size_t)v * N_CLS + c * 8;
    f4_t t0v = *(const f4_t*)pt;
    f4_t t1v = *(((const f4_t*)pt) + 1);
    t0v += tk * a0;
    t1v += tk * a1;
    *(f4_t*)pt = t0v;
    *(((f4_t*)pt) + 1) = t1v;
}

// ---------------------------------------------------------------- log_softmax
__global__ __launch_bounds__(256) void lsm_kernel(float* __restrict__ out) {
    int wid = (blockIdx.x * 256 + threadIdx.x) >> 6;
    int lane = threadIdx.x & 63;
    if (wid >= N_NODES) return;
    float x = (lane < N_CLS) ? out[wid * N_CLS + lane] : -INFINITY;
    float m = x;
#pragma unroll
    for (int o = 32; o > 0; o >>= 1) m = fmaxf(m, __shfl_xor(m, o, 64));
    float e = (lane < N_CLS) ? expf(x - m) : 0.f;
    float s = e;
#pragma unroll
    for (int o = 32; o > 0; o >>= 1) s += __shfl_xor(s, o, 64);
    float r = x - m - logf(s);
    if (lane < N_CLS) out[wid * N_CLS + lane] = r;
}

// ---------------------------------------------------------------- launch

extern "C" void kernel_launch(void* const* d_in, const int* in_sizes, int n_in,
                              void* d_out, int out_size, void* d_ws, size_t ws_size,
                              hipStream_t stream) {
    const float* feat = (const float*)d_in[0];
    const float* W1   = (const float*)d_in[1];
    const float* b1   = (const float*)d_in[2];
    const float* W2   = (const float*)d_in[3];
    const float* b2   = (const float*)d_in[4];
    const float* temp = (const float*)d_in[5];
    const int*   src  = (const int*)d_in[6];
    const int*   dst  = (const int*)d_in[7];
    float* out = (float*)d_out;

    // workspace layout (bytes). degp region reused for W1T/W2T after scan_write.
    // (harness poisons ~819MB workspace each iteration -> ws_size >> 50MB)
    char* ws = (char*)d_ws;
    int*   degp    = (int*)(ws + 0);          // 3,200,000 B (dead after scan_write)
    short* W1T     = (short*)(ws + 0);        //   262,144 B (overlaps degp)
    short* W2T     = (short*)(ws + 262144);   //    32,768 B (overlaps degp)
    float* dnorm   = (float*)(ws + 3200000);  //   400,000 B
    int*   rowptrp = (int*)(ws + 3600000);    // 3,200,004 B
    int*   cursor  = (int*)(ws + 6800016);    // 3,200,000 B
    int2*  epair   = (int2*)(ws + 10000016);  // 13,600,000 B
    short* h0      = (short*)(ws + 23600016); // 12,800,000 B (bf16, [N][64] padded)
    short* h1      = (short*)(ws + 36400016); // 12,800,000 B
    int*   blocksum = (int*)(ws + 49200016);  //     3,128 B
    int*   blockoff = (int*)(ws + 49203152);  //     3,128 B  -> end 49,206,280

    init_degp_kernel<<<(NPN + 255) / 256, 256, 0, stream>>>(degp);
    count_dst_kernel<<<(N_EDGES + 255) / 256, 256, 0, stream>>>(src, dst, degp);
    rsqrt_deg_kernel<<<(N_NODES + 255) / 256, 256, 0, stream>>>(degp, dnorm);
    scan_partial_kernel<<<SCANB, 1024, 0, stream>>>(degp, blocksum);
    scan_blocks_kernel<<<1, 1024, 0, stream>>>(blocksum, blockoff);
    scan_write_kernel<<<SCANB, 1024, 0, stream>>>(degp, blockoff, rowptrp, cursor);
    cvt_w1_kernel<<<512, 256, 0, stream>>>(W1, W1T);
    cvt_w2_kernel<<<64, 256, 0, stream>>>(W2, W2T);
    scatter_edges_kernel<<<(N_EDGES + 255) / 256, 256, 0, stream>>>(src, dst, dnorm, cursor,
                                                                    epair);
    scatter_self_kernel<<<(N_NODES + 255) / 256, 256, 0, stream>>>(dnorm, cursor, epair);

    mlp_kernel<<<(N_NODES + 63) / 64, 256, 0, stream>>>(feat, W1T, b1, W2T, b2, temp, h0, out);

    short* hc = h0;
    short* hn = h1;
    for (int k = 0; k < K_HOPS; ++k) {
        prop_kernel<<<PGRID, 256, 0, stream>>>(hc, hn, rowptrp, epair, out, temp, k + 1);
        short* t = hc; hc = hn; hn = t;
    }

    lsm_kernel<<<(N_NODES / 4), 256, 0, stream>>>(out);
}